// Round 1
// baseline (778.720 us; speedup 1.0000x reference)
//
#include <hip/hip_runtime.h>
#include <stdint.h>

// ---------- types & helpers ----------
typedef __attribute__((ext_vector_type(8))) short bf16x8;
typedef __attribute__((ext_vector_type(4))) float f32x4;
typedef __attribute__((ext_vector_type(4))) short s16x4;

__device__ __forceinline__ float bf2f(short u) {
  union { float f; unsigned int i; } c; c.i = ((unsigned int)(unsigned short)u) << 16; return c.f;
}
__device__ __forceinline__ short f2bf(float f) {
  union { float f; unsigned int i; } c; c.f = f;
  return (short)((c.i + 0x7FFFu + ((c.i >> 16) & 1u)) >> 16);  // RNE
}
__device__ __forceinline__ float wredsum(float v) {
#pragma unroll
  for (int o = 32; o; o >>= 1) v += __shfl_xor(v, o);
  return v;
}
__device__ __forceinline__ void gload16(const short* g, short* l) {
  __builtin_amdgcn_global_load_lds(
      (const __attribute__((address_space(1))) unsigned int*)g,
      (__attribute__((address_space(3))) unsigned int*)l, 16, 0, 0);
}

// ---------- weight transpose+cast: out[c][r] = in[r][c] (f32 -> bf16) ----------
__global__ void k_transpose(const float* __restrict__ in, short* __restrict__ out,
                            int R, int C) {
  int idx = blockIdx.x * 256 + threadIdx.x;
  if (idx >= R * C) return;
  int c = idx / R, r = idx - c * R;
  out[idx] = f2bf(in[(size_t)r * C + c]);
}

// ---------- state LN -> q (pre-scaled), k ----------
__global__ __launch_bounds__(128) void k_qk(
    const float* __restrict__ state, const float* __restrict__ g, const float* __restrict__ b,
    const float* __restrict__ Wq, const float* __restrict__ bq,
    const float* __restrict__ Wk, const float* __restrict__ bk,
    float* __restrict__ qbuf, float* __restrict__ kbuf) {
  __shared__ float sn[64];
  const int l = blockIdx.x, tid = threadIdx.x;
  if (tid < 64) {
    float v = state[l * 64 + tid];
    float mean = wredsum(v) * (1.f / 64.f);
    float d = v - mean;
    float var = wredsum(d * d) * (1.f / 64.f);
    sn[tid] = d * rsqrtf(var + 1e-5f) * g[tid] + b[tid];
  }
  __syncthreads();
  float qa = 0.f, ka = 0.f;
#pragma unroll 8
  for (int k = 0; k < 64; ++k) {
    float s = sn[k];
    qa += s * Wq[k * 128 + tid];
    ka += s * Wk[k * 128 + tid];
  }
  qbuf[l * 128 + tid] = (qa + bq[tid]) * 0.25f;  // SCALE = 16^-0.5
  kbuf[l * 128 + tid] = ka + bk[tid];
}

// ---------- logits + distance mask + softmax -> att bf16 [4][512][512] ----------
__global__ __launch_bounds__(256) void k_att(
    const float* __restrict__ qbuf, const float* __restrict__ kbuf,
    const float* __restrict__ xyz, short* __restrict__ att) {
  __shared__ float qs[32];
  __shared__ float cai[3];
  __shared__ float wm[4], wsm[4];
  const int i = blockIdx.x, h = blockIdx.y, t = threadIdx.x;
  if (t < 32) qs[t] = qbuf[i * 128 + h * 32 + t];
  if (t < 3) cai[t] = xyz[i * 9 + 3 + t];  // CA atom
  __syncthreads();
  const float bin2 = (h == 0) ? 64.f : (h == 1) ? 144.f : (h == 2) ? 256.f : 400.f;
  float lg[2];
#pragma unroll
  for (int p = 0; p < 2; ++p) {
    int j = t + p * 256;
    const float* kr = kbuf + j * 128 + h * 32;
    float a = 0.f;
#pragma unroll 8
    for (int d = 0; d < 32; ++d) a += qs[d] * kr[d];
    float dx = cai[0] - xyz[j * 9 + 3], dy = cai[1] - xyz[j * 9 + 4], dz = cai[2] - xyz[j * 9 + 5];
    float d2 = dx * dx + dy * dy + dz * dz;
    lg[p] = (d2 < bin2) ? a : a - 1e9f;
  }
  const int wave = t >> 6, lane = t & 63;
  float m = fmaxf(lg[0], lg[1]);
#pragma unroll
  for (int o = 32; o; o >>= 1) m = fmaxf(m, __shfl_xor(m, o));
  if (lane == 0) wm[wave] = m;
  __syncthreads();
  m = fmaxf(fmaxf(wm[0], wm[1]), fmaxf(wm[2], wm[3]));
  float e0 = __expf(lg[0] - m), e1 = __expf(lg[1] - m);
  float s = wredsum(e0 + e1);
  if (lane == 0) wsm[wave] = s;
  __syncthreads();
  float inv = 1.f / (wsm[0] + wsm[1] + wsm[2] + wsm[3]);
  size_t base = ((size_t)h * 512 + i) * 512;
  att[base + t] = f2bf(e0 * inv);
  att[base + t + 256] = f2bf(e1 * inv);
}

// ---------- msa LN (rows of 256) -> bf16 ----------
__global__ __launch_bounds__(256) void k_msaln(
    const float* __restrict__ msa, const float* __restrict__ g, const float* __restrict__ b,
    short* __restrict__ msa_n) {
  const int wave = threadIdx.x >> 6, lane = threadIdx.x & 63;
  const size_t row = (size_t)blockIdx.x * 4 + wave;
  const float4 v = ((const float4*)(msa + row * 256))[lane];
  float mean = wredsum(v.x + v.y + v.z + v.w) * (1.f / 256.f);
  float d0 = v.x - mean, d1 = v.y - mean, d2 = v.z - mean, d3 = v.w - mean;
  float var = wredsum(d0 * d0 + d1 * d1 + d2 * d2 + d3 * d3) * (1.f / 256.f);
  float rs = rsqrtf(var + 1e-5f);
  const int c = lane * 4;
  s16x4 o;
  o[0] = f2bf(d0 * rs * g[c + 0] + b[c + 0]);
  o[1] = f2bf(d1 * rs * g[c + 1] + b[c + 1]);
  o[2] = f2bf(d2 * rs * g[c + 2] + b[c + 2]);
  o[3] = f2bf(d3 * rs * g[c + 3] + b[c + 3]);
  *(s16x4*)(msa_n + row * 256 + c) = o;
}

// ---------- O(+bv) LN + residual -> msa2; ff-LN(msa2) -> msa2ln ----------
__global__ __launch_bounds__(256) void k_msa2(
    const short* __restrict__ O, const float* __restrict__ bv,
    const short* __restrict__ msa_n,
    const float* __restrict__ go, const float* __restrict__ bo,
    const float* __restrict__ gf, const float* __restrict__ bfp,
    short* __restrict__ msa2, short* __restrict__ msa2ln) {
  const int wave = threadIdx.x >> 6, lane = threadIdx.x & 63;
  const size_t row = (size_t)blockIdx.x * 4 + wave;
  const int c = lane * 4;
  s16x4 ov = *(const s16x4*)(O + row * 256 + c);
  float t0 = bf2f(ov[0]) + bv[c + 0], t1 = bf2f(ov[1]) + bv[c + 1];
  float t2 = bf2f(ov[2]) + bv[c + 2], t3 = bf2f(ov[3]) + bv[c + 3];
  float mean = wredsum(t0 + t1 + t2 + t3) * (1.f / 256.f);
  float d0 = t0 - mean, d1 = t1 - mean, d2 = t2 - mean, d3 = t3 - mean;
  float var = wredsum(d0 * d0 + d1 * d1 + d2 * d2 + d3 * d3) * (1.f / 256.f);
  float rs = rsqrtf(var + 1e-5f);
  s16x4 nv = *(const s16x4*)(msa_n + row * 256 + c);
  float m0 = bf2f(nv[0]) + d0 * rs * go[c + 0] + bo[c + 0];
  float m1 = bf2f(nv[1]) + d1 * rs * go[c + 1] + bo[c + 1];
  float m2 = bf2f(nv[2]) + d2 * rs * go[c + 2] + bo[c + 2];
  float m3 = bf2f(nv[3]) + d3 * rs * go[c + 3] + bo[c + 3];
  float mean2 = wredsum(m0 + m1 + m2 + m3) * (1.f / 256.f);
  float e0 = m0 - mean2, e1 = m1 - mean2, e2 = m2 - mean2, e3 = m3 - mean2;
  float var2 = wredsum(e0 * e0 + e1 * e1 + e2 * e2 + e3 * e3) * (1.f / 256.f);
  float rs2 = rsqrtf(var2 + 1e-5f);
  s16x4 w1; w1[0] = f2bf(m0); w1[1] = f2bf(m1); w1[2] = f2bf(m2); w1[3] = f2bf(m3);
  *(s16x4*)(msa2 + row * 256 + c) = w1;
  s16x4 w2;
  w2[0] = f2bf(e0 * rs2 * gf[c + 0] + bfp[c + 0]);
  w2[1] = f2bf(e1 * rs2 * gf[c + 1] + bfp[c + 1]);
  w2[2] = f2bf(e2 * rs2 * gf[c + 2] + bfp[c + 2]);
  w2[3] = f2bf(e3 * rs2 * gf[c + 3] + bfp[c + 3]);
  *(s16x4*)(msa2ln + row * 256 + c) = w2;
}

// ---------- generic C = A @ B^T GEMM (m97-style: global_load_lds, BK=32) ----------
// A [M][K] lda, B [N][K] ldb (both bf16 row-major, K-contiguous), C row-major ldc.
// ATTN: batched over blockIdx.z = n_local*4 + h for the attention-out einsum.
template <int BM, int BN, int WR, int WC, bool ATTN, bool BIAS, bool RELU, bool RES, bool OUTBF>
__global__ __launch_bounds__(256) void gemm_nt(
    const short* __restrict__ A, const short* __restrict__ B, void* __restrict__ Cv,
    const float* __restrict__ bias, const short* __restrict__ res,
    int K, int lda, int ldb, int ldc) {
  constexpr int WM = BM / WR, WN = BN / WC;
  constexpr int MF = WM / 16, NF = WN / 16;
  __shared__ alignas(16) short As[BM * 32];
  __shared__ alignas(16) short Bs[BN * 32];
  const int tid = threadIdx.x;
  const int wave = tid >> 6, lane = tid & 63;
  const int wr = wave / WC, wc = wave % WC;
  size_t offA = 0, offB = 0, offC = 0;
  if (ATTN) {
    const int z = blockIdx.z, h = z & 3, nl = z >> 2;
    offA = (size_t)h * (512 * 512);
    offB = (size_t)(h * 64) * ldb + (size_t)nl * 512;
    offC = (size_t)nl * 512 * ldc + (size_t)h * 64;
  }
  const int rowBase = blockIdx.x * BM;
  const int colBase = blockIdx.y * BN;
  const f32x4 fzero = {0.f, 0.f, 0.f, 0.f};
  f32x4 acc[MF][NF];
#pragma unroll
  for (int m = 0; m < MF; ++m)
#pragma unroll
    for (int n = 0; n < NF; ++n) acc[m][n] = fzero;

  const int srow = lane >> 2;           // staging: row within 16-row chunk
  const int skoff = (lane & 3) << 3;    // staging: k element offset (8-elem steps)
  const int fr = lane & 15, fk = (lane >> 4) << 3;

  for (int kt = 0; kt < K; kt += 32) {
    __syncthreads();
    for (int ch = wave; ch < BM / 16; ch += 4) {
      const short* src = A + offA + (size_t)(rowBase + ch * 16 + srow) * lda + kt + skoff;
      gload16(src, &As[ch * 512]);
    }
    for (int ch = wave; ch < BN / 16; ch += 4) {
      const short* src = B + offB + (size_t)(colBase + ch * 16 + srow) * ldb + kt + skoff;
      gload16(src, &Bs[ch * 512]);
    }
    __syncthreads();
    bf16x8 af[MF], bfr[NF];
#pragma unroll
    for (int m = 0; m < MF; ++m)
      af[m] = *(const bf16x8*)&As[(wr * WM + m * 16 + fr) * 32 + fk];
#pragma unroll
    for (int n = 0; n < NF; ++n)
      bfr[n] = *(const bf16x8*)&Bs[(wc * WN + n * 16 + fr) * 32 + fk];
#pragma unroll
    for (int m = 0; m < MF; ++m)
#pragma unroll
      for (int n = 0; n < NF; ++n)
        acc[m][n] = __builtin_amdgcn_mfma_f32_16x16x32_bf16(af[m], bfr[n], acc[m][n], 0, 0, 0);
  }

  const int er = (lane >> 4) << 2;  // C/D: row = er+j, col = lane&15 (m89-verified)
  const int ec = lane & 15;
#pragma unroll
  for (int m = 0; m < MF; ++m) {
#pragma unroll
    for (int n = 0; n < NF; ++n) {
      const int col = colBase + wc * WN + n * 16 + ec;
      const float bb = BIAS ? bias[col] : 0.f;
#pragma unroll
      for (int j = 0; j < 4; ++j) {
        const int row = rowBase + wr * WM + m * 16 + er + j;
        float v = acc[m][n][j] + bb;
        if (RELU) v = fmaxf(v, 0.f);
        const size_t ci = offC + (size_t)row * ldc + col;
        if (RES) v += bf2f(res[ci]);
        if (OUTBF) ((short*)Cv)[ci] = f2bf(v);
        else ((float*)Cv)[ci] = v;
      }
    }
  }
}

// ---------- host ----------
extern "C" void kernel_launch(void* const* d_in, const int* in_sizes, int n_in,
                              void* d_out, int out_size, void* d_ws, size_t ws_size,
                              hipStream_t stream) {
  (void)in_sizes; (void)n_in; (void)out_size;
  const float* xyz  = (const float*)d_in[0];
  const float* state= (const float*)d_in[1];
  const float* msa  = (const float*)d_in[2];
  const float* g_msa= (const float*)d_in[3];
  const float* b_msa= (const float*)d_in[4];
  const float* g_st = (const float*)d_in[5];
  const float* b_st = (const float*)d_in[6];
  const float* Wq   = (const float*)d_in[7];
  const float* bq   = (const float*)d_in[8];
  const float* Wk   = (const float*)d_in[9];
  const float* bk   = (const float*)d_in[10];
  const float* Wv   = (const float*)d_in[11];
  const float* bv   = (const float*)d_in[12];
  const float* g_out= (const float*)d_in[13];
  const float* b_out= (const float*)d_in[14];
  const float* g_ff = (const float*)d_in[15];
  const float* b_ff = (const float*)d_in[16];
  const float* W1   = (const float*)d_in[17];
  const float* b1   = (const float*)d_in[18];
  const float* W2   = (const float*)d_in[19];
  const float* b2   = (const float*)d_in[20];
  float* out = (float*)d_out;

  // pick N-chunking (NB n-rows per chunk) so scratch fits ws_size
  int NC = 16;
  {
    const size_t per_n = 5ull * 512 * 256 * 2 + 512ull * 1024 * 2;  // 2.25 MiB per n
    const int cands[5] = {1, 2, 4, 8, 16};
    for (int ci = 0; ci < 5; ++ci) {
      size_t need = 8ull * 1024 * 1024 + (size_t)(256 / cands[ci]) * per_n;
      if (need <= ws_size) { NC = cands[ci]; break; }
    }
  }
  const int NB = 256 / NC;

  char* ws = (char*)d_ws;
  size_t off = 0;
  auto alloc = [&](size_t bytes) -> void* {
    void* p = ws + off;
    off = (off + bytes + 255) & ~(size_t)255;
    return p;
  };
  float* qbuf = (float*)alloc(512 * 128 * 4);
  float* kbuf = (float*)alloc(512 * 128 * 4);
  short* att  = (short*)alloc((size_t)4 * 512 * 512 * 2);
  short* Wvt  = (short*)alloc(65536 * 2);
  short* W1t  = (short*)alloc(262144 * 2);
  short* W2t  = (short*)alloc(262144 * 2);
  const size_t chrows = (size_t)NB * 512;           // rows per chunk
  short* msa_n_c = (short*)alloc(chrows * 256 * 2);
  short* Vt_c    = (short*)alloc(chrows * 256 * 2); // [256 c][NB*512 nj]
  short* O_c     = (short*)alloc(chrows * 256 * 2);
  short* msa2_c  = (short*)alloc(chrows * 256 * 2);
  short* msa2ln_c= (short*)alloc(chrows * 256 * 2);
  short* hdn_c   = (short*)alloc(chrows * 1024 * 2);

  // front-end (chunk-independent)
  k_transpose<<<(65536 + 255) / 256, 256, 0, stream>>>(Wv, Wvt, 256, 256);
  k_transpose<<<(262144 + 255) / 256, 256, 0, stream>>>(W1, W1t, 256, 1024);
  k_transpose<<<(262144 + 255) / 256, 256, 0, stream>>>(W2, W2t, 1024, 256);
  k_qk<<<512, 128, 0, stream>>>(state, g_st, b_st, Wq, bq, Wk, bk, qbuf, kbuf);
  k_att<<<dim3(512, 4), 256, 0, stream>>>(qbuf, kbuf, xyz, att);

  for (int cc = 0; cc < NC; ++cc) {
    const size_t nOff = (size_t)cc * NB;
    // 1. msa LN for this n-chunk
    k_msaln<<<NB * 128, 256, 0, stream>>>(msa + nOff * 512 * 256, g_msa, b_msa, msa_n_c);
    // 2. V^T[c][nj] = Wv^T @ msa_n^T   (bv folded into k_msa2 via softmax-sum==1)
    gemm_nt<128, 128, 2, 2, false, false, false, false, true>
        <<<dim3(2, NB * 4), 256, 0, stream>>>(Wvt, msa_n_c, Vt_c, nullptr, nullptr,
                                              256, 256, 256, NB * 512);
    // 3. O[nj][c] = att_h @ V^T  (batched over z = n_local*4 + h)
    gemm_nt<128, 64, 2, 2, true, false, false, false, true>
        <<<dim3(4, 1, NB * 4), 256, 0, stream>>>(att, Vt_c, O_c, nullptr, nullptr,
                                                 512, 512, NB * 512, 256);
    // 4. msa2 = msa_n + LN(O+bv); msa2ln = ffLN(msa2)
    k_msa2<<<NB * 128, 256, 0, stream>>>(O_c, bv, msa_n_c, g_out, b_out, g_ff, b_ff,
                                         msa2_c, msa2ln_c);
    // 5. hdn = relu(msa2ln @ W1 + b1)
    gemm_nt<128, 128, 2, 2, false, true, true, false, true>
        <<<dim3(NB * 4, 8), 256, 0, stream>>>(msa2ln_c, W1t, hdn_c, b1, nullptr,
                                              256, 256, 256, 1024);
    // 6. out = msa2 + hdn @ W2 + b2 (f32)
    gemm_nt<128, 128, 2, 2, false, true, false, true, false>
        <<<dim3(NB * 4, 2), 256, 0, stream>>>(hdn_c, W2t, out + nOff * 512 * 256, b2, msa2_c,
                                              1024, 1024, 1024, 256);
  }
}

// Round 2
// 718.304 us; speedup vs baseline: 1.0841x; 1.0841x over previous
//
#include <hip/hip_runtime.h>
#include <stdint.h>

// ---------- types & helpers ----------
typedef __attribute__((ext_vector_type(8))) short bf16x8;
typedef __attribute__((ext_vector_type(4))) float f32x4;
typedef __attribute__((ext_vector_type(4))) short s16x4;

__device__ __forceinline__ float bf2f(short u) {
  union { float f; unsigned int i; } c; c.i = ((unsigned int)(unsigned short)u) << 16; return c.f;
}
__device__ __forceinline__ short f2bf(float f) {
  union { float f; unsigned int i; } c; c.f = f;
  return (short)((c.i + 0x7FFFu + ((c.i >> 16) & 1u)) >> 16);  // RNE
}
__device__ __forceinline__ float wredsum(float v) {
#pragma unroll
  for (int o = 32; o; o >>= 1) v += __shfl_xor(v, o);
  return v;
}
__device__ __forceinline__ void gload16(const short* g, short* l) {
  __builtin_amdgcn_global_load_lds(
      (const __attribute__((address_space(1))) unsigned int*)g,
      (__attribute__((address_space(3))) unsigned int*)l, 16, 0, 0);
}

// ---------- coalesced weight transpose+cast: out[c][r] = in[r][c] (f32 -> bf16) ----------
// grid (C/32, R/32), block 256 (32x8)
__global__ __launch_bounds__(256) void k_transpose(const float* __restrict__ in,
                                                   short* __restrict__ out, int R, int C) {
  __shared__ float t[32][33];
  const int bx = blockIdx.x, by = blockIdx.y;
  const int tx = threadIdx.x & 31, ty = threadIdx.x >> 5;
#pragma unroll
  for (int i = 0; i < 4; ++i)
    t[ty + i * 8][tx] = in[(size_t)(by * 32 + ty + i * 8) * C + bx * 32 + tx];
  __syncthreads();
#pragma unroll
  for (int i = 0; i < 4; ++i)
    out[(size_t)(bx * 32 + ty + i * 8) * R + by * 32 + tx] = f2bf(t[tx][ty + i * 8]);
}

// ---------- state LN -> q (pre-scaled), k ----------
__global__ __launch_bounds__(128) void k_qk(
    const float* __restrict__ state, const float* __restrict__ g, const float* __restrict__ b,
    const float* __restrict__ Wq, const float* __restrict__ bq,
    const float* __restrict__ Wk, const float* __restrict__ bk,
    float* __restrict__ qbuf, float* __restrict__ kbuf) {
  __shared__ float sn[64];
  const int l = blockIdx.x, tid = threadIdx.x;
  if (tid < 64) {
    float v = state[l * 64 + tid];
    float mean = wredsum(v) * (1.f / 64.f);
    float d = v - mean;
    float var = wredsum(d * d) * (1.f / 64.f);
    sn[tid] = d * rsqrtf(var + 1e-5f) * g[tid] + b[tid];
  }
  __syncthreads();
  float qa = 0.f, ka = 0.f;
#pragma unroll 8
  for (int k = 0; k < 64; ++k) {
    float s = sn[k];
    qa += s * Wq[k * 128 + tid];
    ka += s * Wk[k * 128 + tid];
  }
  qbuf[l * 128 + tid] = (qa + bq[tid]) * 0.25f;  // SCALE = 16^-0.5
  kbuf[l * 128 + tid] = ka + bk[tid];
}

// ---------- logits + distance mask + softmax -> att bf16 [4][512][512] ----------
__global__ __launch_bounds__(256) void k_att(
    const float* __restrict__ qbuf, const float* __restrict__ kbuf,
    const float* __restrict__ xyz, short* __restrict__ att) {
  __shared__ float qs[32];
  __shared__ float cai[3];
  __shared__ float wm[4], wsm[4];
  const int i = blockIdx.x, h = blockIdx.y, t = threadIdx.x;
  if (t < 32) qs[t] = qbuf[i * 128 + h * 32 + t];
  if (t < 3) cai[t] = xyz[i * 9 + 3 + t];  // CA atom
  __syncthreads();
  const float bin2 = (h == 0) ? 64.f : (h == 1) ? 144.f : (h == 2) ? 256.f : 400.f;
  float lg[2];
#pragma unroll
  for (int p = 0; p < 2; ++p) {
    int j = t + p * 256;
    const float* kr = kbuf + j * 128 + h * 32;
    float a = 0.f;
#pragma unroll 8
    for (int d = 0; d < 32; ++d) a += qs[d] * kr[d];
    float dx = cai[0] - xyz[j * 9 + 3], dy = cai[1] - xyz[j * 9 + 4], dz = cai[2] - xyz[j * 9 + 5];
    float d2 = dx * dx + dy * dy + dz * dz;
    lg[p] = (d2 < bin2) ? a : a - 1e9f;
  }
  const int wave = t >> 6, lane = t & 63;
  float m = fmaxf(lg[0], lg[1]);
#pragma unroll
  for (int o = 32; o; o >>= 1) m = fmaxf(m, __shfl_xor(m, o));
  if (lane == 0) wm[wave] = m;
  __syncthreads();
  m = fmaxf(fmaxf(wm[0], wm[1]), fmaxf(wm[2], wm[3]));
  float e0 = __expf(lg[0] - m), e1 = __expf(lg[1] - m);
  float s = wredsum(e0 + e1);
  if (lane == 0) wsm[wave] = s;
  __syncthreads();
  float inv = 1.f / (wsm[0] + wsm[1] + wsm[2] + wsm[3]);
  size_t base = ((size_t)h * 512 + i) * 512;
  att[base + t] = f2bf(e0 * inv);
  att[base + t + 256] = f2bf(e1 * inv);
}

// ---------- msa LN (rows of 256) -> bf16 ----------
__global__ __launch_bounds__(256) void k_msaln(
    const float* __restrict__ msa, const float* __restrict__ g, const float* __restrict__ b,
    short* __restrict__ msa_n) {
  const int wave = threadIdx.x >> 6, lane = threadIdx.x & 63;
  const size_t row = (size_t)blockIdx.x * 4 + wave;
  const float4 v = ((const float4*)(msa + row * 256))[lane];
  float mean = wredsum(v.x + v.y + v.z + v.w) * (1.f / 256.f);
  float d0 = v.x - mean, d1 = v.y - mean, d2 = v.z - mean, d3 = v.w - mean;
  float var = wredsum(d0 * d0 + d1 * d1 + d2 * d2 + d3 * d3) * (1.f / 256.f);
  float rs = rsqrtf(var + 1e-5f);
  const int c = lane * 4;
  s16x4 o;
  o[0] = f2bf(d0 * rs * g[c + 0] + b[c + 0]);
  o[1] = f2bf(d1 * rs * g[c + 1] + b[c + 1]);
  o[2] = f2bf(d2 * rs * g[c + 2] + b[c + 2]);
  o[3] = f2bf(d3 * rs * g[c + 3] + b[c + 3]);
  *(s16x4*)(msa_n + row * 256 + c) = o;
}

// ---------- O(+bv) LN + residual -> msa2; ff-LN(msa2) -> msa2ln ----------
__global__ __launch_bounds__(256) void k_msa2(
    const short* __restrict__ O, const float* __restrict__ bv,
    const short* __restrict__ msa_n,
    const float* __restrict__ go, const float* __restrict__ bo,
    const float* __restrict__ gf, const float* __restrict__ bfp,
    short* __restrict__ msa2, short* __restrict__ msa2ln) {
  const int wave = threadIdx.x >> 6, lane = threadIdx.x & 63;
  const size_t row = (size_t)blockIdx.x * 4 + wave;
  const int c = lane * 4;
  s16x4 ov = *(const s16x4*)(O + row * 256 + c);
  float t0 = bf2f(ov[0]) + bv[c + 0], t1 = bf2f(ov[1]) + bv[c + 1];
  float t2 = bf2f(ov[2]) + bv[c + 2], t3 = bf2f(ov[3]) + bv[c + 3];
  float mean = wredsum(t0 + t1 + t2 + t3) * (1.f / 256.f);
  float d0 = t0 - mean, d1 = t1 - mean, d2 = t2 - mean, d3 = t3 - mean;
  float var = wredsum(d0 * d0 + d1 * d1 + d2 * d2 + d3 * d3) * (1.f / 256.f);
  float rs = rsqrtf(var + 1e-5f);
  s16x4 nv = *(const s16x4*)(msa_n + row * 256 + c);
  float m0 = bf2f(nv[0]) + d0 * rs * go[c + 0] + bo[c + 0];
  float m1 = bf2f(nv[1]) + d1 * rs * go[c + 1] + bo[c + 1];
  float m2 = bf2f(nv[2]) + d2 * rs * go[c + 2] + bo[c + 2];
  float m3 = bf2f(nv[3]) + d3 * rs * go[c + 3] + bo[c + 3];
  float mean2 = wredsum(m0 + m1 + m2 + m3) * (1.f / 256.f);
  float e0 = m0 - mean2, e1 = m1 - mean2, e2 = m2 - mean2, e3 = m3 - mean2;
  float var2 = wredsum(e0 * e0 + e1 * e1 + e2 * e2 + e3 * e3) * (1.f / 256.f);
  float rs2 = rsqrtf(var2 + 1e-5f);
  s16x4 w1; w1[0] = f2bf(m0); w1[1] = f2bf(m1); w1[2] = f2bf(m2); w1[3] = f2bf(m3);
  *(s16x4*)(msa2 + row * 256 + c) = w1;
  s16x4 w2;
  w2[0] = f2bf(e0 * rs2 * gf[c + 0] + bfp[c + 0]);
  w2[1] = f2bf(e1 * rs2 * gf[c + 1] + bfp[c + 1]);
  w2[2] = f2bf(e2 * rs2 * gf[c + 2] + bfp[c + 2]);
  w2[3] = f2bf(e3 * rs2 * gf[c + 3] + bfp[c + 3]);
  *(s16x4*)(msa2ln + row * 256 + c) = w2;
}

// ---------- C = A @ B^T GEMM, BK=64, dbuf prefetch, XOR-swizzled LDS ----------
// MODE 1: attention-out batched over z = nl*4+h. MODE 2: V-gemm batched over z = n.
template <int BM, int BN, int MODE>
__global__ __launch_bounds__(256) void gemm_nt(
    const short* __restrict__ A, const short* __restrict__ B, short* __restrict__ C,
    int K, int lda, int ldb, int ldc) {
  constexpr int WM = BM / 2, WN = BN / 2;
  constexpr int MF = WM / 16, NF = WN / 16;
  __shared__ alignas(16) short As[2][BM * 64];
  __shared__ alignas(16) short Bs[2][BN * 64];
  const int tid = threadIdx.x, wave = tid >> 6, lane = tid & 63;
  const int wr = wave >> 1, wc = wave & 1;
  const int fr = lane & 15;
  size_t offA = 0, offB = 0, offC = 0;
  if (MODE == 1) {
    const int z = blockIdx.z, h = z & 3, nl = z >> 2;
    offA = (size_t)h * (512 * 512);
    offB = (size_t)nl * (256 * 512) + (size_t)(h * 64) * 512;
    offC = (size_t)nl * (512 * 256) + (size_t)(h * 64);
  } else if (MODE == 2) {
    const size_t z = blockIdx.z;
    offB = z * (512 * 256);
    offC = z * (256 * 512);
  }
  const int rowBase = blockIdx.x * BM, colBase = blockIdx.y * BN;

  auto stage = [&](const short* G, size_t goff, int ld, int rb, int kt, short* dst, int nrow) {
    for (int ch = wave; ch < nrow / 8; ch += 4) {
      const int r = ch * 8 + (lane >> 3);
      const int kel = (((lane & 7) * 16) ^ ((r & 7) << 4)) >> 1;
      gload16(G + goff + (size_t)(rb + r) * ld + kt + kel, dst + ch * 512);
    }
  };

  const f32x4 fzero = {0.f, 0.f, 0.f, 0.f};
  f32x4 acc[MF][NF];
#pragma unroll
  for (int m = 0; m < MF; ++m)
#pragma unroll
    for (int n = 0; n < NF; ++n) acc[m][n] = fzero;

  stage(A, offA, lda, rowBase, 0, As[0], BM);
  stage(B, offB, ldb, colBase, 0, Bs[0], BN);
  int buf = 0;
  for (int kt = 0; kt < K; kt += 64) {
    __syncthreads();
    if (kt + 64 < K) {
      stage(A, offA, lda, rowBase, kt + 64, As[buf ^ 1], BM);
      stage(B, offB, ldb, colBase, kt + 64, Bs[buf ^ 1], BN);
    }
    bf16x8 af[MF][2], bfr[NF][2];
#pragma unroll
    for (int m = 0; m < MF; ++m)
#pragma unroll
      for (int kk = 0; kk < 2; ++kk) {
        const int r = wr * WM + m * 16 + fr;
        const int b = kk * 64 + (lane >> 4) * 16;
        af[m][kk] = *(const bf16x8*)&As[buf][r * 64 + ((b ^ ((r & 7) << 4)) >> 1)];
      }
#pragma unroll
    for (int n = 0; n < NF; ++n)
#pragma unroll
      for (int kk = 0; kk < 2; ++kk) {
        const int r = wc * WN + n * 16 + fr;
        const int b = kk * 64 + (lane >> 4) * 16;
        bfr[n][kk] = *(const bf16x8*)&Bs[buf][r * 64 + ((b ^ ((r & 7) << 4)) >> 1)];
      }
#pragma unroll
    for (int m = 0; m < MF; ++m)
#pragma unroll
      for (int n = 0; n < NF; ++n)
#pragma unroll
        for (int kk = 0; kk < 2; ++kk)
          acc[m][n] = __builtin_amdgcn_mfma_f32_16x16x32_bf16(af[m][kk], bfr[n][kk], acc[m][n], 0, 0, 0);
    buf ^= 1;
  }

  const int er = (lane >> 4) << 2, ec = lane & 15;
#pragma unroll
  for (int m = 0; m < MF; ++m)
#pragma unroll
    for (int n = 0; n < NF; ++n) {
      const int col = colBase + wc * WN + n * 16 + ec;
#pragma unroll
      for (int j = 0; j < 4; ++j) {
        const int row = rowBase + wr * WM + m * 16 + er + j;
        C[offC + (size_t)row * ldc + col] = f2bf(acc[m][n][j]);
      }
    }
}

// ---------- fused FFN: out = msa2 + relu(msa2ln@W1+b1)@W2 + b2 ----------
// 512 thr (8 waves 2x4), BM=64 rows/block, A in regs, W1/W2 via 2x32KB ring, P in LDS.
__global__ __launch_bounds__(512) void k_ffn(
    const short* __restrict__ msa2ln, const short* __restrict__ msa2,
    const short* __restrict__ W1t, const short* __restrict__ W2t,
    const float* __restrict__ b1, const float* __restrict__ b2,
    float* __restrict__ out) {
  __shared__ alignas(16) short ring[2][16384];  // 32 KB each
  __shared__ alignas(16) short P[8192];         // [64][128] swizzled, 16 KB
  const int tid = threadIdx.x, wave = tid >> 6, lane = tid & 63;
  const int wr = wave >> 2, wc = wave & 3;
  const int fr = lane & 15, er = (lane >> 4) << 2, ec = fr;
  const size_t rowBase = (size_t)blockIdx.x * 64;

  // stage A tile [64][256] swizzled into ring[0]
  for (int ch = wave; ch < 32; ch += 8) {
    const int r = ch * 2 + (lane >> 5);
    const int kel = (((lane & 31) * 16) ^ ((r & 7) << 4)) >> 1;
    gload16(msa2ln + (rowBase + r) * 256 + kel, &ring[0][ch * 512]);
  }
  __syncthreads();
  bf16x8 areg[2][8];
#pragma unroll
  for (int m = 0; m < 2; ++m)
#pragma unroll
    for (int kk = 0; kk < 8; ++kk) {
      const int r = wr * 32 + m * 16 + fr;
      const int b = kk * 64 + (lane >> 4) * 16;
      areg[m][kk] = *(const bf16x8*)&ring[0][r * 256 + ((b ^ ((r & 7) << 4)) >> 1)];
    }
  __syncthreads();  // A reads done before ring[0] reused

  auto stageW = [&](int s, short* dst) {
    const int f8s = s >> 2, q = s & 3;
    if (q < 2) {  // W1 chunk q: [128 f-rows][128 k], stride 256B
      for (int ch = wave; ch < 32; ch += 8) {
        const int r = ch * 4 + (lane >> 4);
        const int kel = (((lane & 15) * 16) ^ ((r & 7) << 4)) >> 1;
        gload16(W1t + (size_t)(f8s * 128 + r) * 256 + q * 128 + kel, dst + ch * 512);
      }
    } else {      // W2 chunk q-2: [256 c-rows][64 k], stride 128B
      for (int ch = wave; ch < 32; ch += 8) {
        const int r = ch * 8 + (lane >> 3);
        const int kel = (((lane & 7) * 16) ^ ((r & 7) << 4)) >> 1;
        gload16(W2t + (size_t)r * 1024 + f8s * 128 + (q - 2) * 64 + kel, dst + ch * 512);
      }
    }
  };

  const f32x4 fzero = {0.f, 0.f, 0.f, 0.f};
  f32x4 acc2[2][4];
#pragma unroll
  for (int m = 0; m < 2; ++m)
#pragma unroll
    for (int n = 0; n < 4; ++n) acc2[m][n] = fzero;

#define G1STEP(QC)                                                                   \
  {                                                                                  \
    bf16x8 bfr[2][4];                                                                \
    _Pragma("unroll") for (int n = 0; n < 2; ++n) {                                  \
      _Pragma("unroll") for (int kk = 0; kk < 4; ++kk) {                             \
        const int r = wc * 32 + n * 16 + fr;                                         \
        const int b = kk * 64 + (lane >> 4) * 16;                                    \
        bfr[n][kk] = *(const bf16x8*)&buf[r * 128 + ((b ^ ((r & 7) << 4)) >> 1)];    \
      }                                                                              \
    }                                                                                \
    _Pragma("unroll") for (int m = 0; m < 2; ++m) {                                  \
      _Pragma("unroll") for (int n = 0; n < 2; ++n) {                                \
        _Pragma("unroll") for (int kk = 0; kk < 4; ++kk)                             \
          acc1[m][n] = __builtin_amdgcn_mfma_f32_16x16x32_bf16(                      \
              areg[m][QC * 4 + kk], bfr[n][kk], acc1[m][n], 0, 0, 0);                \
      }                                                                              \
    }                                                                                \
  }

#define G2STEP(CC)                                                                   \
  {                                                                                  \
    bf16x8 a2[2][2], bfr[4][2];                                                      \
    _Pragma("unroll") for (int m = 0; m < 2; ++m) {                                  \
      _Pragma("unroll") for (int kk = 0; kk < 2; ++kk) {                             \
        const int r = wr * 32 + m * 16 + fr;                                         \
        const int b = CC * 128 + kk * 64 + (lane >> 4) * 16;                         \
        a2[m][kk] = *(const bf16x8*)&P[r * 128 + ((b ^ ((r & 7) << 4)) >> 1)];       \
      }                                                                              \
    }                                                                                \
    _Pragma("unroll") for (int n = 0; n < 4; ++n) {                                  \
      _Pragma("unroll") for (int kk = 0; kk < 2; ++kk) {                             \
        const int r = wc * 64 + n * 16 + fr;                                         \
        const int b = kk * 64 + (lane >> 4) * 16;                                    \
        bfr[n][kk] = *(const bf16x8*)&buf[r * 64 + ((b ^ ((r & 7) << 4)) >> 1)];     \
      }                                                                              \
    }                                                                                \
    _Pragma("unroll") for (int m = 0; m < 2; ++m) {                                  \
      _Pragma("unroll") for (int n = 0; n < 4; ++n) {                                \
        _Pragma("unroll") for (int kk = 0; kk < 2; ++kk)                             \
          acc2[m][n] = __builtin_amdgcn_mfma_f32_16x16x32_bf16(                      \
              a2[m][kk], bfr[n][kk], acc2[m][n], 0, 0, 0);                           \
      }                                                                              \
    }                                                                                \
  }

  int s = 0;
  stageW(0, ring[0]);
#pragma unroll 1
  for (int f8 = 0; f8 < 8; ++f8) {
    f32x4 acc1[2][2];
#pragma unroll
    for (int m = 0; m < 2; ++m)
#pragma unroll
      for (int n = 0; n < 2; ++n) acc1[m][n] = fzero;
    float b1v[2];
    {
      __syncthreads();
      stageW(s + 1, ring[(s + 1) & 1]);
      b1v[0] = b1[f8 * 128 + wc * 32 + ec];
      b1v[1] = b1[f8 * 128 + wc * 32 + 16 + ec];
      const short* buf = ring[s & 1];
      G1STEP(0);
      ++s;
    }
    {
      __syncthreads();
      stageW(s + 1, ring[(s + 1) & 1]);
      const short* buf = ring[s & 1];
      G1STEP(1);
      ++s;
    }
    // P write (relu + bias + cvt), consumed after next barrier
#pragma unroll
    for (int m = 0; m < 2; ++m)
#pragma unroll
      for (int n = 0; n < 2; ++n) {
        const int col2 = (wc * 32 + n * 16 + ec) * 2;
#pragma unroll
        for (int j = 0; j < 4; ++j) {
          const int row = wr * 32 + m * 16 + er + j;
          P[row * 128 + ((col2 ^ ((row & 7) << 4)) >> 1)] = f2bf(fmaxf(acc1[m][n][j] + b1v[n], 0.f));
        }
      }
    {
      __syncthreads();
      stageW(s + 1, ring[(s + 1) & 1]);
      const short* buf = ring[s & 1];
      G2STEP(0);
      ++s;
    }
    {
      __syncthreads();
      if (s + 1 < 32) stageW(s + 1, ring[(s + 1) & 1]);
      const short* buf = ring[s & 1];
      G2STEP(1);
      ++s;
    }
  }
#undef G1STEP
#undef G2STEP

#pragma unroll
  for (int m = 0; m < 2; ++m)
#pragma unroll
    for (int n = 0; n < 4; ++n) {
      const int col = wc * 64 + n * 16 + ec;
      const float bb = b2[col];
#pragma unroll
      for (int j = 0; j < 4; ++j) {
        const size_t row = rowBase + wr * 32 + m * 16 + er + j;
        out[row * 256 + col] = acc2[m][n][j] + bb + bf2f(msa2[row * 256 + col]);
      }
    }
}

// ---------- host ----------
extern "C" void kernel_launch(void* const* d_in, const int* in_sizes, int n_in,
                              void* d_out, int out_size, void* d_ws, size_t ws_size,
                              hipStream_t stream) {
  (void)in_sizes; (void)n_in; (void)out_size;
  const float* xyz  = (const float*)d_in[0];
  const float* state= (const float*)d_in[1];
  const float* msa  = (const float*)d_in[2];
  const float* g_msa= (const float*)d_in[3];
  const float* b_msa= (const float*)d_in[4];
  const float* g_st = (const float*)d_in[5];
  const float* b_st = (const float*)d_in[6];
  const float* Wq   = (const float*)d_in[7];
  const float* bq   = (const float*)d_in[8];
  const float* Wk   = (const float*)d_in[9];
  const float* bk   = (const float*)d_in[10];
  const float* Wv   = (const float*)d_in[11];
  const float* bv   = (const float*)d_in[12];
  const float* g_out= (const float*)d_in[13];
  const float* b_out= (const float*)d_in[14];
  const float* g_ff = (const float*)d_in[15];
  const float* b_ff = (const float*)d_in[16];
  const float* W1   = (const float*)d_in[17];
  const float* b1   = (const float*)d_in[18];
  const float* W2   = (const float*)d_in[19];
  const float* b2   = (const float*)d_in[20];
  float* out = (float*)d_out;

  // pick N-chunking so scratch fits ws_size
  int NC = 16;
  {
    const size_t per_n = 5ull * 512 * 256 * 2;  // msa_n, Vt, O, msa2, msa2ln
    const int cands[5] = {1, 2, 4, 8, 16};
    for (int ci = 0; ci < 5; ++ci) {
      size_t need = 8ull * 1024 * 1024 + (size_t)(256 / cands[ci]) * per_n;
      if (need <= ws_size) { NC = cands[ci]; break; }
    }
  }
  const int NB = 256 / NC;

  char* ws = (char*)d_ws;
  size_t off = 0;
  auto alloc = [&](size_t bytes) -> void* {
    void* p = ws + off;
    off = (off + bytes + 255) & ~(size_t)255;
    return p;
  };
  float* qbuf = (float*)alloc(512 * 128 * 4);
  float* kbuf = (float*)alloc(512 * 128 * 4);
  short* att  = (short*)alloc((size_t)4 * 512 * 512 * 2);
  short* Wvt  = (short*)alloc(65536 * 2);
  short* W1t  = (short*)alloc(262144 * 2);
  short* W2t  = (short*)alloc(262144 * 2);
  const size_t chrows = (size_t)NB * 512;
  short* msa_n_c = (short*)alloc(chrows * 256 * 2);
  short* Vt_c    = (short*)alloc(chrows * 256 * 2);  // [n][256 c][512 j]
  short* O_c     = (short*)alloc(chrows * 256 * 2);
  short* msa2_c  = (short*)alloc(chrows * 256 * 2);
  short* msa2ln_c= (short*)alloc(chrows * 256 * 2);

  // front-end (chunk-independent)
  k_transpose<<<dim3(8, 8), 256, 0, stream>>>(Wv, Wvt, 256, 256);
  k_transpose<<<dim3(32, 8), 256, 0, stream>>>(W1, W1t, 256, 1024);
  k_transpose<<<dim3(8, 32), 256, 0, stream>>>(W2, W2t, 1024, 256);
  k_qk<<<512, 128, 0, stream>>>(state, g_st, b_st, Wq, bq, Wk, bk, qbuf, kbuf);
  k_att<<<dim3(512, 4), 256, 0, stream>>>(qbuf, kbuf, xyz, att);

  for (int cc = 0; cc < NC; ++cc) {
    const size_t nOff = (size_t)cc * NB;
    // 1. msa LN for this n-chunk
    k_msaln<<<NB * 128, 256, 0, stream>>>(msa + nOff * 512 * 256, g_msa, b_msa, msa_n_c);
    // 2. per-n: Vt[n][c][j] = Wvt @ msa_n[n]^T  (bv folded into k_msa2)
    gemm_nt<128, 128, 2><<<dim3(2, 4, NB), 256, 0, stream>>>(
        Wvt, msa_n_c, Vt_c, 256, 256, 256, 512);
    // 3. O[nj][c] = att_h @ Vt[n]  (batched over z = nl*4 + h)
    gemm_nt<128, 64, 1><<<dim3(4, 1, NB * 4), 256, 0, stream>>>(
        att, Vt_c, O_c, 512, 512, 512, 256);
    // 4. msa2 = msa_n + LN(O+bv); msa2ln = ffLN(msa2)
    k_msa2<<<NB * 128, 256, 0, stream>>>(O_c, bv, msa_n_c, g_out, b_out, g_ff, b_ff,
                                         msa2_c, msa2ln_c);
    // 5+6 fused: out = msa2 + relu(msa2ln@W1+b1)@W2 + b2
    k_ffn<<<NB * 8, 512, 0, stream>>>(msa2ln_c, msa2_c, W1t, W2t, b1, b2,
                                      out + nOff * 512 * 256);
  }
}